// Round 1
// baseline (307.781 us; speedup 1.0000x reference)
//
#include <hip/hip_runtime.h>
#include <hip/hip_bf16.h>

// CausalSelfAttention (B=2, T=2048, D=1024, H=16, hd=64).
// fp32 in, fp32 out storage (bf16-space grading). bf16 MFMA pipeline.
// R14: attn was latency-bound on the longest serial wave (i=63 block = 32
// K-tiles; MfmaUtil 7.7%, Occupancy 14%, HBM 3%). Fixed-max softmax makes
// K-partials associative -> split K 4 ways across 4 waves per block
// (kt = wave, wave+4, ...), LDS tree-combine of (acc, l) at the end.
// Per-tile __syncthreads replaced by wave-local lgkmcnt(0) fence (sP is
// wave-private; block barrier would deadlock under divergent trip counts).
// Longest chain 32 -> 9 tiles, resident waves 2048 -> 4096.
// GEMM side: R11/R12 glds kernels (proven). transpose_v natural order (R10).

typedef __bf16 bf16;
typedef __bf16 bf16x8 __attribute__((ext_vector_type(8)));
typedef float f32x4 __attribute__((ext_vector_type(4)));

__device__ __forceinline__ bf16 f2bf(float f) {
    unsigned u = __builtin_bit_cast(unsigned, f);
    u += 0x7fffu + ((u >> 16) & 1u);          // RNE
    unsigned short h = (unsigned short)(u >> 16);
    return __builtin_bit_cast(bf16, h);
}
__device__ __forceinline__ bf16 trunc_bf(float f) {
    unsigned u = __builtin_bit_cast(unsigned, f);
    return __builtin_bit_cast(bf16, (unsigned short)(u >> 16));
}

__device__ __forceinline__ bf16x8 ld8f(const float* p) {
    f32x4 a = *(const f32x4*)p;
    f32x4 b = *(const f32x4*)(p + 4);
    bf16x8 r;
#pragma unroll
    for (int i = 0; i < 4; i++) { r[i] = f2bf(a[i]); r[i + 4] = f2bf(b[i]); }
    return r;
}

__device__ __forceinline__ void st_out(bf16* p, float v)  { *p = f2bf(v); }
__device__ __forceinline__ void st_out(float* p, float v) { *p = v; }

// wave-local LDS ordering: compiler memory barrier + drain lgkm.
// Sufficient for same-wave LDS write->read visibility (sP is wave-private).
__device__ __forceinline__ void lds_fence() {
    asm volatile("s_waitcnt lgkmcnt(0)" ::: "memory");
}

// fp32 -> bf16 bulk convert
__global__ __launch_bounds__(256) void cvt_bf16(const float* __restrict__ src,
                                                bf16* __restrict__ dst, int n) {
    int i = (blockIdx.x * 256 + threadIdx.x) * 8;
    if (i < n) *(bf16x8*)&dst[i] = ld8f(&src[i]);
}

// async global->LDS, 16B per lane; LDS dest = uniform base + lane*16
__device__ __forceinline__ void glds16(const bf16* g, bf16* l) {
    __builtin_amdgcn_global_load_lds(
        (const __attribute__((address_space(1))) void*)g,
        (__attribute__((address_space(3))) void*)l, 16, 0, 0);
}

// ---------------------------------------------------------------------------
// C[M,N] = A[., lda, +aoff] @ W[N,K]^T, both bf16. global_load_lds staging,
// XOR chunk swizzle (R11-proven). Tile 128 x BN, BK=32, 4 waves.
// ---------------------------------------------------------------------------
template <typename TC, int BN>
__global__ __launch_bounds__(256) void gemm_glds(const bf16* __restrict__ A, int lda, int aoff,
                                                 const bf16* __restrict__ W,
                                                 TC* __restrict__ C, int N, int K) {
    constexpr int NI = (BN == 128) ? 4 : 2;
    __shared__ bf16 sA[128 * 32];
    __shared__ bf16 sW[BN * 32];
    const int bm = blockIdx.x * 128, bn = blockIdx.y * BN;
    const int tid = threadIdx.x;
    const int wave = tid >> 6, lane = tid & 63;
    const int quad = lane >> 4, l16 = lane & 15;
    const int rbase = (BN == 128) ? (wave >> 1) * 64 : wave * 32;
    const int cbase = (BN == 128) ? (wave & 1) * 64 : 0;
    const int r16 = lane >> 2, cl = lane & 3;
    const int gch = cl ^ ((r16 >> 1) & 3);
    const int sl  = (l16 >> 1) & 3;

    f32x4 acc[NI][4] = {};

    for (int k0 = 0; k0 < K; k0 += 32) {
        __syncthreads();
#pragma unroll
        for (int t = 0; t < 2; t++) {
            int row = wave * 32 + t * 16 + r16;
            glds16(&A[(size_t)(bm + row) * lda + aoff + k0 + gch * 8],
                   &sA[(wave * 32 + t * 16) * 32]);
        }
        if (BN == 128) {
#pragma unroll
            for (int t = 0; t < 2; t++) {
                int row = wave * 32 + t * 16 + r16;
                glds16(&W[(size_t)(bn + row) * K + k0 + gch * 8],
                       &sW[(wave * 32 + t * 16) * 32]);
            }
        } else {
            int row = wave * 16 + r16;
            glds16(&W[(size_t)(bn + row) * K + k0 + gch * 8], &sW[(wave * 16) * 32]);
        }
        __syncthreads();

        bf16x8 af[NI], bfr[4];
#pragma unroll
        for (int i = 0; i < NI; i++)
            af[i] = *(bf16x8*)&sA[(rbase + i * 16 + l16) * 32 + (quad ^ sl) * 8];
#pragma unroll
        for (int j = 0; j < 4; j++)
            bfr[j] = *(bf16x8*)&sW[(cbase + j * 16 + l16) * 32 + (quad ^ sl) * 8];
#pragma unroll
        for (int i = 0; i < NI; i++)
#pragma unroll
            for (int j = 0; j < 4; j++)
                acc[i][j] = __builtin_amdgcn_mfma_f32_16x16x32_bf16(
                    af[i], bfr[j], acc[i][j], 0, 0, 0);
    }

#pragma unroll
    for (int i = 0; i < NI; i++)
#pragma unroll
        for (int j = 0; j < 4; j++)
#pragma unroll
            for (int r = 0; r < 4; r++) {
                int row = bm + rbase + i * 16 + quad * 4 + r;
                int col = bn + cbase + j * 16 + l16;
                st_out(&C[(size_t)row * N + col], acc[i][j][r]);
            }
}

// ---------------------------------------------------------------------------
// vt[bh][d][t] = qkv[b][t][2048 + h*64 + d].  Natural order (R10).
// ---------------------------------------------------------------------------
__global__ __launch_bounds__(256) void transpose_v(const bf16* __restrict__ qkv,
                                                   bf16* __restrict__ vt) {
    __shared__ bf16 s[64][72];
    const int tt = blockIdx.x;
    const int bh = blockIdx.y;
    const int b = bh >> 4, h = bh & 15;
    const int tid = threadIdx.x;

    for (int c = tid; c < 512; c += 256) {
        int t = c >> 3, dc = (c & 7) * 8;
        *(bf16x8*)&s[t][dc] =
            *(const bf16x8*)&qkv[((size_t)(b * 2048 + tt * 64 + t)) * 3072 + 2048 + h * 64 + dc];
    }
    __syncthreads();
    for (int c = tid; c < 512; c += 256) {
        int d = c >> 3, tc = (c & 7) * 8;
        bf16x8 o;
#pragma unroll
        for (int e = 0; e < 8; e++) o[e] = s[tc + e][d];
        *(bf16x8*)&vt[((size_t)bh * 64 + d) * 2048 + tt * 64 + tc] = o;
    }
}

// ---------------------------------------------------------------------------
// Flash causal attention, fixed-max softmax, 4-way K-split across 4 waves.
// Wave w handles K-tiles {w, w+4, ...}; partial (acc, l) are associative
// (fixed max), tree-combined through LDS at the end. Per-tile sync is a
// wave-local lgkmcnt fence (sP is wave-private). A/B K-register prefetch
// pipeline (R13) kept per wave.
// ---------------------------------------------------------------------------
__global__ __launch_bounds__(256, 4) void attn(bf16* __restrict__ qkv,
                                               const bf16* __restrict__ vt) {
    const int bh = blockIdx.x;
    const int i  = 63 - blockIdx.y;
    const int b = bh >> 4, h = bh & 15;
    const int tid  = threadIdx.x;
    const int wave = tid >> 6;
    const int lane = tid & 63;
    const int quad = lane >> 4, l16 = lane & 15;

    // 4 wave-private P tiles (32x90 bf16 each) during the loop; reused as the
    // fp32 combine buffer (2 slots x 64 lanes x stride 41) afterwards.
    __shared__ __align__(16) unsigned char smem[23040];
    bf16*  sPw = (bf16*)smem + wave * 32 * 90;
    float* sC  = (float*)smem;

    bf16* base = qkv + (size_t)b * 2048 * 3072;
    const bf16* vbh = vt + (size_t)bh * 64 * 2048;
    const int qb = i * 32;
    const int kint = i >> 1;
    const float SC = 0.125f * 1.44269504f;

    bf16x8 qa[2][2];
#pragma unroll
    for (int rt = 0; rt < 2; rt++)
#pragma unroll
        for (int c = 0; c < 2; c++)
            qa[rt][c] = *(const bf16x8*)&base[(size_t)(qb + rt * 16 + l16) * 3072 +
                                              h * 64 + c * 32 + quad * 8];

    f32x4 acc[2][4] = {};
    float lpart[2][4] = {};

    auto loadK = [&](int kt, bf16x8 (&kb)[4][2]) {
#pragma unroll
        for (int j = 0; j < 4; j++) {
            const bf16* kr = &base[(size_t)(kt * 64 + j * 16 + l16) * 3072 + 1024 + h * 64];
            kb[j][0] = *(const bf16x8*)&kr[quad * 8];
            kb[j][1] = *(const bf16x8*)&kr[32 + quad * 8];
        }
    };

    auto body = [&](int kt, bool tail, bf16x8 (&kb)[4][2]) {
        // V loads issued here, consumed at the end (latency hidden by S+exp)
        bf16x8 vb[4][2];
#pragma unroll
        for (int dt = 0; dt < 4; dt++) {
            const bf16* vr = &vbh[(size_t)(dt * 16 + l16) * 2048 + kt * 64];
            vb[dt][0] = *(const bf16x8*)&vr[quad * 8];
            vb[dt][1] = *(const bf16x8*)&vr[32 + quad * 8];
        }

        f32x4 S[2][4] = {};
#pragma unroll
        for (int j = 0; j < 4; j++)
#pragma unroll
            for (int rt = 0; rt < 2; rt++) {
                S[rt][j] = __builtin_amdgcn_mfma_f32_16x16x32_bf16(qa[rt][0], kb[j][0], S[rt][j], 0, 0, 0);
                S[rt][j] = __builtin_amdgcn_mfma_f32_16x16x32_bf16(qa[rt][1], kb[j][1], S[rt][j], 0, 0, 0);
            }

#pragma unroll
        for (int rt = 0; rt < 2; rt++)
#pragma unroll
            for (int j = 0; j < 4; j++)
#pragma unroll
                for (int r = 0; r < 4; r++) {
                    float p = exp2f(S[rt][j][r] * SC - 8.0f);
                    if (tail) {
                        int kg = kt * 64 + j * 16 + l16;
                        int qg = qb + rt * 16 + quad * 4 + r;
                        p = (kg > qg) ? 0.0f : p;
                    }
                    lpart[rt][r] += p;
                    sPw[(rt * 16 + quad * 4 + r) * 90 + j * 16 + l16] = trunc_bf(p);
                }
        lds_fence();   // wave-local: P writes visible before reads

        bf16x8 pa[2][2];
#pragma unroll
        for (int rt = 0; rt < 2; rt++) {
            pa[rt][0] = *(bf16x8*)&sPw[(rt * 16 + l16) * 90 + quad * 8];
            pa[rt][1] = *(bf16x8*)&sPw[(rt * 16 + l16) * 90 + 32 + quad * 8];
        }
#pragma unroll
        for (int dt = 0; dt < 4; dt++)
#pragma unroll
            for (int rt = 0; rt < 2; rt++) {
                acc[rt][dt] = __builtin_amdgcn_mfma_f32_16x16x32_bf16(pa[rt][0], vb[dt][0], acc[rt][dt], 0, 0, 0);
                acc[rt][dt] = __builtin_amdgcn_mfma_f32_16x16x32_bf16(pa[rt][1], vb[dt][1], acc[rt][dt], 0, 0, 0);
            }
        lds_fence();   // wave-local: P reads done before next tile overwrites
    };

    // per-wave K-loop: tiles kt = wave, wave+4, ... <= kint, A/B prefetch
    if (wave <= kint) {
        bf16x8 kbA[4][2], kbB[4][2];
        int kt = wave;
        loadK(kt, kbA);
        while (true) {
            if (kt + 4 <= kint) loadK(kt + 4, kbB);
            body(kt, kt == kint, kbA);
            kt += 4;
            if (kt > kint) break;
            if (kt + 4 <= kint) loadK(kt + 4, kbA);
            body(kt, kt == kint, kbB);
            kt += 4;
            if (kt > kint) break;
        }
    }

    // ---- cross-wave combine: acc/l partials are associative (fixed max) ----
    auto publish = [&](int slot) {
        float* p = &sC[(size_t)(slot * 64 + lane) * 41];
#pragma unroll
        for (int rt = 0; rt < 2; rt++)
#pragma unroll
            for (int dt = 0; dt < 4; dt++)
#pragma unroll
                for (int r = 0; r < 4; r++)
                    p[rt * 16 + dt * 4 + r] = acc[rt][dt][r];
#pragma unroll
        for (int rt = 0; rt < 2; rt++)
#pragma unroll
            for (int r = 0; r < 4; r++)
                p[32 + rt * 4 + r] = lpart[rt][r];
    };
    auto absorb = [&](int slot) {
        const float* p = &sC[(size_t)(slot * 64 + lane) * 41];
#pragma unroll
        for (int rt = 0; rt < 2; rt++)
#pragma unroll
            for (int dt = 0; dt < 4; dt++)
#pragma unroll
                for (int r = 0; r < 4; r++)
                    acc[rt][dt][r] += p[rt * 16 + dt * 4 + r];
#pragma unroll
        for (int rt = 0; rt < 2; rt++)
#pragma unroll
            for (int r = 0; r < 4; r++)
                lpart[rt][r] += p[32 + rt * 4 + r];
    };

    __syncthreads();                       // all waves done with sP
    if (wave & 1) publish(wave >> 1);      // waves 1,3 -> slots 0,1
    __syncthreads();
    if (wave == 0) absorb(0);
    else if (wave == 2) absorb(1);
    __syncthreads();
    if (wave == 2) publish(0);             // wave 2 (holds 2+3) -> slot 0
    __syncthreads();
    if (wave != 0) return;
    absorb(0);                             // wave 0 now holds the full sums

    // epilogue: reduce l across 16-lane row group, scale, store
#pragma unroll
    for (int off = 1; off < 16; off <<= 1)
#pragma unroll
        for (int rt = 0; rt < 2; rt++)
#pragma unroll
            for (int r = 0; r < 4; r++)
                lpart[rt][r] += __shfl_xor(lpart[rt][r], off);

#pragma unroll
    for (int rt = 0; rt < 2; rt++)
#pragma unroll
        for (int r = 0; r < 4; r++) {
            float inv = 1.0f / lpart[rt][r];
            int row = qb + rt * 16 + quad * 4 + r;
#pragma unroll
            for (int dt = 0; dt < 4; dt++) {
                int col = h * 64 + dt * 16 + l16;
                base[(size_t)row * 3072 + 2048 + col] = f2bf(acc[rt][dt][r] * inv);
            }
        }
}

extern "C" void kernel_launch(void* const* d_in, const int* in_sizes, int n_in,
                              void* d_out, int out_size, void* d_ws, size_t ws_size,
                              hipStream_t stream) {
    (void)out_size; (void)ws_size;
    const float *x = (const float*)d_in[0], *w_qkv = (const float*)d_in[1],
                *w_proj = (const float*)d_in[2];
    for (int i = 0; i < n_in; i++) {
        if (in_sizes[i] == 4194304) x = (const float*)d_in[i];
        else if (in_sizes[i] == 3145728) w_qkv = (const float*)d_in[i];
        else if (in_sizes[i] == 1048576) w_proj = (const float*)d_in[i];
    }

    float* out = (float*)d_out;                    // [4096,1024] fp32
    bf16* xb   = (bf16*)d_out;                     // 8.4MB scratch in d_out
    bf16* qkv  = (bf16*)d_ws;                      // [4096,3072] bf16 (25.2MB)
    bf16* r2   = qkv + (size_t)4096 * 3072;        // 8.4MB: wqb -> vt -> wpb
    bf16* wqb  = r2;
    bf16* vt   = r2;
    bf16* wpb  = r2;

    cvt_bf16<<<dim3(2048), dim3(256), 0, stream>>>(x, xb, 4096 * 1024);
    cvt_bf16<<<dim3(1536), dim3(256), 0, stream>>>(w_qkv, wqb, 3072 * 1024);
    gemm_glds<bf16, 128><<<dim3(32, 24), dim3(256), 0, stream>>>(
        xb, 1024, 0, wqb, qkv, 3072, 1024);
    transpose_v<<<dim3(32, 32), dim3(256), 0, stream>>>(qkv, vt);
    attn<<<dim3(32, 64), dim3(256), 0, stream>>>(qkv, vt);
    cvt_bf16<<<dim3(512), dim3(256), 0, stream>>>(w_proj, wpb, 1024 * 1024);
    gemm_glds<float, 128><<<dim3(32, 8), dim3(256), 0, stream>>>(
        qkv, 3072, 2048, wpb, out, 1024, 1024);
}

// Round 2
// 226.960 us; speedup vs baseline: 1.3561x; 1.3561x over previous
//
#include <hip/hip_runtime.h>
#include <hip/hip_bf16.h>

// CausalSelfAttention (B=2, T=2048, D=1024, H=16, hd=64).
// fp32 in, fp32 out storage (bf16-space grading). bf16 MFMA pipeline.
// R15: R14's 4-way K-split across waves was correct in structure but
// __launch_bounds__(256,4) capped VGPR at 128 -> body needs ~190 -> massive
// scratch spill (VGPR 64, FETCH 244MB, WRITE 388MB, hbm 49% peak, attn 165us).
// Fix: lb(256,2) -> VGPR cap 256 (R13's body ran at 124 under the same cap).
// Keeps: fixed-max softmax K-partial associativity, kt = wave, wave+4, ...,
// wave-local lgkmcnt fences (sP wave-private), LDS tree-combine, A/B K
// prefetch. Longest serial chain 32 -> 9 tiles vs R13.
// GEMM side: R11/R12 glds kernels (proven). transpose_v natural order (R10).

typedef __bf16 bf16;
typedef __bf16 bf16x8 __attribute__((ext_vector_type(8)));
typedef float f32x4 __attribute__((ext_vector_type(4)));

__device__ __forceinline__ bf16 f2bf(float f) {
    unsigned u = __builtin_bit_cast(unsigned, f);
    u += 0x7fffu + ((u >> 16) & 1u);          // RNE
    unsigned short h = (unsigned short)(u >> 16);
    return __builtin_bit_cast(bf16, h);
}
__device__ __forceinline__ bf16 trunc_bf(float f) {
    unsigned u = __builtin_bit_cast(unsigned, f);
    return __builtin_bit_cast(bf16, (unsigned short)(u >> 16));
}

__device__ __forceinline__ bf16x8 ld8f(const float* p) {
    f32x4 a = *(const f32x4*)p;
    f32x4 b = *(const f32x4*)(p + 4);
    bf16x8 r;
#pragma unroll
    for (int i = 0; i < 4; i++) { r[i] = f2bf(a[i]); r[i + 4] = f2bf(b[i]); }
    return r;
}

__device__ __forceinline__ void st_out(bf16* p, float v)  { *p = f2bf(v); }
__device__ __forceinline__ void st_out(float* p, float v) { *p = v; }

// wave-local LDS ordering: compiler memory barrier + drain lgkm.
// Sufficient for same-wave LDS write->read visibility (sP is wave-private).
__device__ __forceinline__ void lds_fence() {
    asm volatile("s_waitcnt lgkmcnt(0)" ::: "memory");
}

// fp32 -> bf16 bulk convert
__global__ __launch_bounds__(256) void cvt_bf16(const float* __restrict__ src,
                                                bf16* __restrict__ dst, int n) {
    int i = (blockIdx.x * 256 + threadIdx.x) * 8;
    if (i < n) *(bf16x8*)&dst[i] = ld8f(&src[i]);
}

// async global->LDS, 16B per lane; LDS dest = uniform base + lane*16
__device__ __forceinline__ void glds16(const bf16* g, bf16* l) {
    __builtin_amdgcn_global_load_lds(
        (const __attribute__((address_space(1))) void*)g,
        (__attribute__((address_space(3))) void*)l, 16, 0, 0);
}

// ---------------------------------------------------------------------------
// C[M,N] = A[., lda, +aoff] @ W[N,K]^T, both bf16. global_load_lds staging,
// XOR chunk swizzle (R11-proven). Tile 128 x BN, BK=32, 4 waves.
// ---------------------------------------------------------------------------
template <typename TC, int BN>
__global__ __launch_bounds__(256) void gemm_glds(const bf16* __restrict__ A, int lda, int aoff,
                                                 const bf16* __restrict__ W,
                                                 TC* __restrict__ C, int N, int K) {
    constexpr int NI = (BN == 128) ? 4 : 2;
    __shared__ bf16 sA[128 * 32];
    __shared__ bf16 sW[BN * 32];
    const int bm = blockIdx.x * 128, bn = blockIdx.y * BN;
    const int tid = threadIdx.x;
    const int wave = tid >> 6, lane = tid & 63;
    const int quad = lane >> 4, l16 = lane & 15;
    const int rbase = (BN == 128) ? (wave >> 1) * 64 : wave * 32;
    const int cbase = (BN == 128) ? (wave & 1) * 64 : 0;
    const int r16 = lane >> 2, cl = lane & 3;
    const int gch = cl ^ ((r16 >> 1) & 3);
    const int sl  = (l16 >> 1) & 3;

    f32x4 acc[NI][4] = {};

    for (int k0 = 0; k0 < K; k0 += 32) {
        __syncthreads();
#pragma unroll
        for (int t = 0; t < 2; t++) {
            int row = wave * 32 + t * 16 + r16;
            glds16(&A[(size_t)(bm + row) * lda + aoff + k0 + gch * 8],
                   &sA[(wave * 32 + t * 16) * 32]);
        }
        if (BN == 128) {
#pragma unroll
            for (int t = 0; t < 2; t++) {
                int row = wave * 32 + t * 16 + r16;
                glds16(&W[(size_t)(bn + row) * K + k0 + gch * 8],
                       &sW[(wave * 32 + t * 16) * 32]);
            }
        } else {
            int row = wave * 16 + r16;
            glds16(&W[(size_t)(bn + row) * K + k0 + gch * 8], &sW[(wave * 16) * 32]);
        }
        __syncthreads();

        bf16x8 af[NI], bfr[4];
#pragma unroll
        for (int i = 0; i < NI; i++)
            af[i] = *(bf16x8*)&sA[(rbase + i * 16 + l16) * 32 + (quad ^ sl) * 8];
#pragma unroll
        for (int j = 0; j < 4; j++)
            bfr[j] = *(bf16x8*)&sW[(cbase + j * 16 + l16) * 32 + (quad ^ sl) * 8];
#pragma unroll
        for (int i = 0; i < NI; i++)
#pragma unroll
            for (int j = 0; j < 4; j++)
                acc[i][j] = __builtin_amdgcn_mfma_f32_16x16x32_bf16(
                    af[i], bfr[j], acc[i][j], 0, 0, 0);
    }

#pragma unroll
    for (int i = 0; i < NI; i++)
#pragma unroll
        for (int j = 0; j < 4; j++)
#pragma unroll
            for (int r = 0; r < 4; r++) {
                int row = bm + rbase + i * 16 + quad * 4 + r;
                int col = bn + cbase + j * 16 + l16;
                st_out(&C[(size_t)row * N + col], acc[i][j][r]);
            }
}

// ---------------------------------------------------------------------------
// vt[bh][d][t] = qkv[b][t][2048 + h*64 + d].  Natural order (R10).
// ---------------------------------------------------------------------------
__global__ __launch_bounds__(256) void transpose_v(const bf16* __restrict__ qkv,
                                                   bf16* __restrict__ vt) {
    __shared__ bf16 s[64][72];
    const int tt = blockIdx.x;
    const int bh = blockIdx.y;
    const int b = bh >> 4, h = bh & 15;
    const int tid = threadIdx.x;

    for (int c = tid; c < 512; c += 256) {
        int t = c >> 3, dc = (c & 7) * 8;
        *(bf16x8*)&s[t][dc] =
            *(const bf16x8*)&qkv[((size_t)(b * 2048 + tt * 64 + t)) * 3072 + 2048 + h * 64 + dc];
    }
    __syncthreads();
    for (int c = tid; c < 512; c += 256) {
        int d = c >> 3, tc = (c & 7) * 8;
        bf16x8 o;
#pragma unroll
        for (int e = 0; e < 8; e++) o[e] = s[tc + e][d];
        *(bf16x8*)&vt[((size_t)bh * 64 + d) * 2048 + tt * 64 + tc] = o;
    }
}

// ---------------------------------------------------------------------------
// Flash causal attention, fixed-max softmax, 4-way K-split across 4 waves.
// Wave w handles K-tiles {w, w+4, ...}; partial (acc, l) are associative
// (fixed max), tree-combined through LDS at the end. Per-tile sync is a
// wave-local lgkmcnt fence (sP is wave-private). A/B K-register prefetch
// pipeline (R13) kept per wave.
// ---------------------------------------------------------------------------
__global__ __launch_bounds__(256, 2) void attn(bf16* __restrict__ qkv,
                                               const bf16* __restrict__ vt) {
    const int bh = blockIdx.x;
    const int i  = 63 - blockIdx.y;
    const int b = bh >> 4, h = bh & 15;
    const int tid  = threadIdx.x;
    const int wave = tid >> 6;
    const int lane = tid & 63;
    const int quad = lane >> 4, l16 = lane & 15;

    // 4 wave-private P tiles (32x90 bf16 each) during the loop; reused as the
    // fp32 combine buffer (2 slots x 64 lanes x stride 41) afterwards.
    __shared__ __align__(16) unsigned char smem[23040];
    bf16*  sPw = (bf16*)smem + wave * 32 * 90;
    float* sC  = (float*)smem;

    bf16* base = qkv + (size_t)b * 2048 * 3072;
    const bf16* vbh = vt + (size_t)bh * 64 * 2048;
    const int qb = i * 32;
    const int kint = i >> 1;
    const float SC = 0.125f * 1.44269504f;

    bf16x8 qa[2][2];
#pragma unroll
    for (int rt = 0; rt < 2; rt++)
#pragma unroll
        for (int c = 0; c < 2; c++)
            qa[rt][c] = *(const bf16x8*)&base[(size_t)(qb + rt * 16 + l16) * 3072 +
                                              h * 64 + c * 32 + quad * 8];

    f32x4 acc[2][4] = {};
    float lpart[2][4] = {};

    auto loadK = [&](int kt, bf16x8 (&kb)[4][2]) {
#pragma unroll
        for (int j = 0; j < 4; j++) {
            const bf16* kr = &base[(size_t)(kt * 64 + j * 16 + l16) * 3072 + 1024 + h * 64];
            kb[j][0] = *(const bf16x8*)&kr[quad * 8];
            kb[j][1] = *(const bf16x8*)&kr[32 + quad * 8];
        }
    };

    auto body = [&](int kt, bool tail, bf16x8 (&kb)[4][2]) {
        // V loads issued here, consumed at the end (latency hidden by S+exp)
        bf16x8 vb[4][2];
#pragma unroll
        for (int dt = 0; dt < 4; dt++) {
            const bf16* vr = &vbh[(size_t)(dt * 16 + l16) * 2048 + kt * 64];
            vb[dt][0] = *(const bf16x8*)&vr[quad * 8];
            vb[dt][1] = *(const bf16x8*)&vr[32 + quad * 8];
        }

        f32x4 S[2][4] = {};
#pragma unroll
        for (int j = 0; j < 4; j++)
#pragma unroll
            for (int rt = 0; rt < 2; rt++) {
                S[rt][j] = __builtin_amdgcn_mfma_f32_16x16x32_bf16(qa[rt][0], kb[j][0], S[rt][j], 0, 0, 0);
                S[rt][j] = __builtin_amdgcn_mfma_f32_16x16x32_bf16(qa[rt][1], kb[j][1], S[rt][j], 0, 0, 0);
            }

#pragma unroll
        for (int rt = 0; rt < 2; rt++)
#pragma unroll
            for (int j = 0; j < 4; j++)
#pragma unroll
                for (int r = 0; r < 4; r++) {
                    float p = exp2f(S[rt][j][r] * SC - 8.0f);
                    if (tail) {
                        int kg = kt * 64 + j * 16 + l16;
                        int qg = qb + rt * 16 + quad * 4 + r;
                        p = (kg > qg) ? 0.0f : p;
                    }
                    lpart[rt][r] += p;
                    sPw[(rt * 16 + quad * 4 + r) * 90 + j * 16 + l16] = trunc_bf(p);
                }
        lds_fence();   // wave-local: P writes visible before reads

        bf16x8 pa[2][2];
#pragma unroll
        for (int rt = 0; rt < 2; rt++) {
            pa[rt][0] = *(bf16x8*)&sPw[(rt * 16 + l16) * 90 + quad * 8];
            pa[rt][1] = *(bf16x8*)&sPw[(rt * 16 + l16) * 90 + 32 + quad * 8];
        }
#pragma unroll
        for (int dt = 0; dt < 4; dt++)
#pragma unroll
            for (int rt = 0; rt < 2; rt++) {
                acc[rt][dt] = __builtin_amdgcn_mfma_f32_16x16x32_bf16(pa[rt][0], vb[dt][0], acc[rt][dt], 0, 0, 0);
                acc[rt][dt] = __builtin_amdgcn_mfma_f32_16x16x32_bf16(pa[rt][1], vb[dt][1], acc[rt][dt], 0, 0, 0);
            }
        lds_fence();   // wave-local: P reads done before next tile overwrites
    };

    // per-wave K-loop: tiles kt = wave, wave+4, ... <= kint, A/B prefetch
    if (wave <= kint) {
        bf16x8 kbA[4][2], kbB[4][2];
        int kt = wave;
        loadK(kt, kbA);
        while (true) {
            if (kt + 4 <= kint) loadK(kt + 4, kbB);
            body(kt, kt == kint, kbA);
            kt += 4;
            if (kt > kint) break;
            if (kt + 4 <= kint) loadK(kt + 4, kbA);
            body(kt, kt == kint, kbB);
            kt += 4;
            if (kt > kint) break;
        }
    }

    // ---- cross-wave combine: acc/l partials are associative (fixed max) ----
    auto publish = [&](int slot) {
        float* p = &sC[(size_t)(slot * 64 + lane) * 41];
#pragma unroll
        for (int rt = 0; rt < 2; rt++)
#pragma unroll
            for (int dt = 0; dt < 4; dt++)
#pragma unroll
                for (int r = 0; r < 4; r++)
                    p[rt * 16 + dt * 4 + r] = acc[rt][dt][r];
#pragma unroll
        for (int rt = 0; rt < 2; rt++)
#pragma unroll
            for (int r = 0; r < 4; r++)
                p[32 + rt * 4 + r] = lpart[rt][r];
    };
    auto absorb = [&](int slot) {
        const float* p = &sC[(size_t)(slot * 64 + lane) * 41];
#pragma unroll
        for (int rt = 0; rt < 2; rt++)
#pragma unroll
            for (int dt = 0; dt < 4; dt++)
#pragma unroll
                for (int r = 0; r < 4; r++)
                    acc[rt][dt][r] += p[rt * 16 + dt * 4 + r];
#pragma unroll
        for (int rt = 0; rt < 2; rt++)
#pragma unroll
            for (int r = 0; r < 4; r++)
                lpart[rt][r] += p[32 + rt * 4 + r];
    };

    __syncthreads();                       // all waves done with sP
    if (wave & 1) publish(wave >> 1);      // waves 1,3 -> slots 0,1
    __syncthreads();
    if (wave == 0) absorb(0);
    else if (wave == 2) absorb(1);
    __syncthreads();
    if (wave == 2) publish(0);             // wave 2 (holds 2+3) -> slot 0
    __syncthreads();
    if (wave != 0) return;
    absorb(0);                             // wave 0 now holds the full sums

    // epilogue: reduce l across 16-lane row group, scale, store
#pragma unroll
    for (int off = 1; off < 16; off <<= 1)
#pragma unroll
        for (int rt = 0; rt < 2; rt++)
#pragma unroll
            for (int r = 0; r < 4; r++)
                lpart[rt][r] += __shfl_xor(lpart[rt][r], off);

#pragma unroll
    for (int rt = 0; rt < 2; rt++)
#pragma unroll
        for (int r = 0; r < 4; r++) {
            float inv = 1.0f / lpart[rt][r];
            int row = qb + rt * 16 + quad * 4 + r;
#pragma unroll
            for (int dt = 0; dt < 4; dt++) {
                int col = h * 64 + dt * 16 + l16;
                base[(size_t)row * 3072 + 2048 + col] = f2bf(acc[rt][dt][r] * inv);
            }
        }
}

extern "C" void kernel_launch(void* const* d_in, const int* in_sizes, int n_in,
                              void* d_out, int out_size, void* d_ws, size_t ws_size,
                              hipStream_t stream) {
    (void)out_size; (void)ws_size;
    const float *x = (const float*)d_in[0], *w_qkv = (const float*)d_in[1],
                *w_proj = (const float*)d_in[2];
    for (int i = 0; i < n_in; i++) {
        if (in_sizes[i] == 4194304) x = (const float*)d_in[i];
        else if (in_sizes[i] == 3145728) w_qkv = (const float*)d_in[i];
        else if (in_sizes[i] == 1048576) w_proj = (const float*)d_in[i];
    }

    float* out = (float*)d_out;                    // [4096,1024] fp32
    bf16* xb   = (bf16*)d_out;                     // 8.4MB scratch in d_out
    bf16* qkv  = (bf16*)d_ws;                      // [4096,3072] bf16 (25.2MB)
    bf16* r2   = qkv + (size_t)4096 * 3072;        // 8.4MB: wqb -> vt -> wpb
    bf16* wqb  = r2;
    bf16* vt   = r2;
    bf16* wpb  = r2;

    cvt_bf16<<<dim3(2048), dim3(256), 0, stream>>>(x, xb, 4096 * 1024);
    cvt_bf16<<<dim3(1536), dim3(256), 0, stream>>>(w_qkv, wqb, 3072 * 1024);
    gemm_glds<bf16, 128><<<dim3(32, 24), dim3(256), 0, stream>>>(
        xb, 1024, 0, wqb, qkv, 3072, 1024);
    transpose_v<<<dim3(32, 32), dim3(256), 0, stream>>>(qkv, vt);
    attn<<<dim3(32, 64), dim3(256), 0, stream>>>(qkv, vt);
    cvt_bf16<<<dim3(512), dim3(256), 0, stream>>>(w_proj, wpb, 1024 * 1024);
    gemm_glds<float, 128><<<dim3(32, 8), dim3(256), 0, stream>>>(
        qkv, 3072, 2048, wpb, out, 1024, 1024);
}